// Round 3
// baseline (121.922 us; speedup 1.0000x reference)
//
#include <hip/hip_runtime.h>
#include <stdint.h>

#define BB 4
#define NN 2000
#define K_PRE 1000
#define KPAD 1024
#define MAXOUT 128
#define NMS_THR 0.3f
#define MASK_IN_VOX (28*28*28)   // 21952
#define MASK_OUT_VOX (32*32*32)  // 32768

// ---------------- rank (stable descending argsort) + regression -------------
// 32 blocks/batch; each block covers 64 i's with 4 threads per i (each scans
// 500 j's), combined via shfl_xor. Winner thread writes order + regressed box.
__global__ __launch_bounds__(256) void rank_kernel(const float* __restrict__ scores,
                                                   const float* __restrict__ proposals,
                                                   const float* __restrict__ deltas,
                                                   int* __restrict__ order,
                                                   float* __restrict__ boxes_ws) {
    int b = blockIdx.x >> 5;
    int blk = blockIdx.x & 31;
    __shared__ float s[NN];
    const float* sb = scores + b * NN;
    for (int u = threadIdx.x; u < NN / 4; u += 256)
        ((float4*)s)[u] = ((const float4*)sb)[u];
    __syncthreads();

    int i = blk * 64 + (threadIdx.x >> 2);
    int q = threadIdx.x & 3;
    float si = (i < NN) ? s[i] : 0.f;
    int cnt = 0;
    int j0 = q * 500;
    const float4* s4 = (const float4*)s;
#pragma unroll 5
    for (int u = 0; u < 125; ++u) {
        float4 v = s4[j0 / 4 + u];
        int j = j0 + u * 4;
        cnt += (v.x > si) + (v.y > si) + (v.z > si) + (v.w > si);
        cnt += ((v.x == si) & (j + 0 < i)) + ((v.y == si) & (j + 1 < i))
             + ((v.z == si) & (j + 2 < i)) + ((v.w == si) & (j + 3 < i));
    }
    cnt += __shfl_xor(cnt, 1);
    cnt += __shfl_xor(cnt, 2);

    if (q == 0 && i < NN && cnt < K_PRE) {
        int rank = cnt;
        order[b * KPAD + rank] = i;
        const float* p = proposals + (size_t)(b * NN + i) * 6;
        const float* d = deltas    + (size_t)(b * NN + i) * 6;
        float py1 = p[0], px1 = p[1], pz1 = p[2], py2 = p[3], px2 = p[4], pz2 = p[5];
        float h = py2 - py1, w = px2 - px1, dd = pz2 - pz1;
        float cy = py1 + 0.5f * h + d[0] * h;
        float cx = px1 + 0.5f * w + d[1] * w;
        float cz = pz1 + 0.5f * dd + d[2] * dd;
        h *= expf(d[3]); w *= expf(d[4]); dd *= expf(d[5]);
        float* bw = boxes_ws + (size_t)b * 6 * KPAD + rank;
        bw[0 * KPAD] = cy - 0.5f * h;  bw[1 * KPAD] = cx - 0.5f * w;  bw[2 * KPAD] = cz - 0.5f * dd;
        bw[3 * KPAD] = cy + 0.5f * h;  bw[4 * KPAD] = cx + 0.5f * w;  bw[5 * KPAD] = cz + 0.5f * dd;
    }
}

// ---------------- suppression bit-matrix build (walk-coalesced layout) ------
// uint16 element (b, g=r>>3, lane=l, j=r&7): bit jj <=> IoU(row r, box 16l+jj) > thr
// Walk's group-g load is then 64 lanes x 16B contiguous.
__global__ __launch_bounds__(256) void build_kernel(const float* __restrict__ boxes_ws,
                                                    unsigned short* __restrict__ maskT) {
    int b = blockIdx.y;
    int rowbase = blockIdx.x * 16;
    __shared__ float sbx[6][1088];     // stride-17 padding: index k + (k>>4)
    int tid = threadIdx.x;
    const float* bw = boxes_ws + (size_t)b * 6 * KPAD;
    for (int k = tid; k < KPAD; k += 256) {
        int ks = k + (k >> 4);
#pragma unroll
        for (int c = 0; c < 6; ++c) sbx[c][ks] = bw[c * KPAD + k];
    }
    __syncthreads();
    int l = tid & 63, lr = tid >> 6;
#pragma unroll
    for (int pss = 0; pss < 4; ++pss) {
        int r = rowbase + pss * 4 + lr;          // max 1007 < 1024 (pad rows harmless)
        int rs = r + (r >> 4);
        float ry1 = sbx[0][rs], rx1 = sbx[1][rs], rz1 = sbx[2][rs];
        float ry2 = sbx[3][rs], rx2 = sbx[4][rs], rz2 = sbx[5][rs];
        float v1 = (ry2 - ry1) * (rx2 - rx1) * (rz2 - rz1);
        uint32_t bits = 0;
#pragma unroll
        for (int j = 0; j < 16; ++j) {
            int ks = 17 * l + j;
            float y1 = sbx[0][ks], x1 = sbx[1][ks], z1 = sbx[2][ks];
            float y2 = sbx[3][ks], x2 = sbx[4][ks], z2 = sbx[5][ks];
            float iy = fmaxf(fminf(ry2, y2) - fmaxf(ry1, y1), 0.f);
            float ix = fmaxf(fminf(rx2, x2) - fmaxf(rx1, x1), 0.f);
            float iz = fmaxf(fminf(rz2, z2) - fmaxf(rz1, z1), 0.f);
            float inter = iy * ix * iz;
            float v2 = (y2 - y1) * (x2 - x1) * (z2 - z1);
            float iou = inter / (v1 + v2 - inter + 1e-8f);
            bits |= (iou > NMS_THR ? 1u : 0u) << j;
        }
        maskT[(((size_t)b * 128 + (r >> 3)) * 64 + l) * 8 + (r & 7)] = (unsigned short)bits;
    }
}

// ---------------- serial greedy walk (1 wave per batch, deep prefetch) ------
__global__ __launch_bounds__(64) void walk_kernel(const unsigned short* __restrict__ maskT,
                                                  const int* __restrict__ order,
                                                  const float* __restrict__ boxes_ws,
                                                  float* __restrict__ out_boxes,
                                                  float* __restrict__ out_bidx,
                                                  int* __restrict__ g_idx,
                                                  float* __restrict__ g_valid) {
    int b = blockIdx.x;
    int lane = threadIdx.x;
    __shared__ short sel_k[MAXOUT];
    // lane l owns suppressed bits for boxes [16l,16l+16); pre-suppress pads >= 1000
    uint32_t sup = (lane == 62) ? 0xFF00u : (lane == 63) ? 0xFFFFu : 0u;
    int nsel = 0;

    const uint4* gb = (const uint4*)maskT + (size_t)b * 128 * 64 + lane;  // +g*64 per group

    auto proc = [&](const uint4& w4, int g) {
        if (nsel >= MAXOUT) return;
        int owner = g >> 1;
        int sh = (g & 1) * 8;
        uint32_t grp = ((uint32_t)__shfl((int)sup, owner) >> sh) & 0xFFu;
        if (grp == 0xFFu) return;
#pragma unroll
        for (int j = 0; j < 8; ++j) {
            if (nsel < MAXOUT && !((grp >> j) & 1u)) {
                uint32_t w32 = ((const uint32_t*)&w4)[j >> 1];
                uint32_t half = (j & 1) ? (w32 >> 16) : (w32 & 0xFFFFu);
                if (lane == 0) sel_k[nsel] = (short)(8 * g + j);
                sup |= half;
                grp |= ((uint32_t)__shfl((int)half, owner) >> sh) & 0xFFu;
                nsel++;
            }
        }
    };

    uint4 buf0[16], buf1[16];
#pragma unroll
    for (int t = 0; t < 16; ++t) buf0[t] = gb[t * 64];
    for (int c = 0; c < 8; c += 2) {
        if (c + 1 < 8) {
#pragma unroll
            for (int t = 0; t < 16; ++t) buf1[t] = gb[((c + 1) * 16 + t) * 64];
        }
#pragma unroll
        for (int t = 0; t < 16; ++t) proc(buf0[t], c * 16 + t);
        if (c + 2 < 8) {
#pragma unroll
            for (int t = 0; t < 16; ++t) buf0[t] = gb[((c + 2) * 16 + t) * 64];
        }
        if (c + 1 < 8) {
#pragma unroll
            for (int t = 0; t < 16; ++t) proc(buf1[t], (c + 1) * 16 + t);
        }
    }

    __builtin_amdgcn_s_waitcnt(0);  // lane0's LDS writes -> visible to whole wave
    const float* bw = boxes_ws + (size_t)b * 6 * KPAD;
#pragma unroll
    for (int s0 = 0; s0 < 2; ++s0) {
        int s = lane + s0 * 64;
        int valid = s < nsel;
        int k = valid ? (int)sel_k[s] : 0;
        int idx = valid ? order[b * KPAD + k] : 0;
        float vf = valid ? 1.f : 0.f;
        g_idx[b * MAXOUT + s] = idx;
        g_valid[b * MAXOUT + s] = vf;
        float* ob = out_boxes + (size_t)(b * MAXOUT + s) * 6;
#pragma unroll
        for (int c = 0; c < 6; ++c) ob[c] = bw[c * KPAD + k] * vf;
        out_bidx[b * MAXOUT + s] = (float)b;
    }
}

// ---------------- mask gather + trilinear 28^3 -> 32^3 ----------------------
// thread = (oy, 4x ox); float4 stores fully coalesced; scalar loads L1-hit.
__global__ __launch_bounds__(256) void resize_kernel(const float* __restrict__ masks,
                                                     const int* __restrict__ g_idx,
                                                     const float* __restrict__ g_valid,
                                                     float* __restrict__ out_masks) {
    int s = blockIdx.x;          // 0..B*MAXOUT-1
    int b = s >> 7;
    int gi = g_idx[s];
    float vf = g_valid[s];
    const float* src = masks + (size_t)(b * NN + gi) * MASK_IN_VOX;
    float* dst = out_masks + (size_t)s * MASK_OUT_VOX;

    int tid = threadIdx.x;
    int oy = tid >> 3;
    int ox0 = (tid & 7) * 4;
    // y weights: loop-invariant per thread
    float syf = 0.875f * oy - 0.0625f;
    int fly = (int)floorf(syf);
    float fy = syf - (float)fly;
    int y0 = max(0, min(27, fly)), y1 = max(0, min(27, fly + 1));

    for (int oz = 0; oz < 32; ++oz) {
        float szf = 0.875f * oz - 0.0625f;
        int flz = (int)floorf(szf);
        float fz = szf - (float)flz;
        int z0 = max(0, min(27, flz)), z1 = max(0, min(27, flz + 1));
        const float* p00 = src + (z0 * 28 + y0) * 28;
        const float* p01 = src + (z0 * 28 + y1) * 28;
        const float* p10 = src + (z1 * 28 + y0) * 28;
        const float* p11 = src + (z1 * 28 + y1) * 28;
        float4 o;
#pragma unroll
        for (int e = 0; e < 4; ++e) {
            int ox = ox0 + e;
            float sx = 0.875f * ox - 0.0625f;
            int flx = (int)floorf(sx);
            float fx = sx - (float)flx;
            int x0 = max(0, min(27, flx)), x1 = max(0, min(27, flx + 1));
            float v000 = p00[x0], v001 = p00[x1];
            float v010 = p01[x0], v011 = p01[x1];
            float v100 = p10[x0], v101 = p10[x1];
            float v110 = p11[x0], v111 = p11[x1];
            float c00 = v000 + fx * (v001 - v000);
            float c01 = v010 + fx * (v011 - v010);
            float c10 = v100 + fx * (v101 - v100);
            float c11 = v110 + fx * (v111 - v110);
            float c0 = c00 + fy * (c01 - c00);
            float c1 = c10 + fy * (c11 - c10);
            (&o.x)[e] = (c0 + fz * (c1 - c0)) * vf;
        }
        *(float4*)(dst + oz * 1024 + oy * 32 + ox0) = o;
    }
}

extern "C" void kernel_launch(void* const* d_in, const int* in_sizes, int n_in,
                              void* d_out, int out_size, void* d_ws, size_t ws_size,
                              hipStream_t stream) {
    const float* proposals = (const float*)d_in[0];
    const float* scores    = (const float*)d_in[1];
    const float* deltas    = (const float*)d_in[2];
    const float* masks     = (const float*)d_in[3];

    float* out = (float*)d_out;
    float* out_boxes = out;                                              // [512,6]
    float* out_masks = out + (size_t)BB * MAXOUT * 6;                    // [512,32768]
    float* out_bidx  = out + (size_t)BB * MAXOUT * 6 + (size_t)BB * MAXOUT * MASK_OUT_VOX;

    char* ws = (char*)d_ws;
    int*            order    = (int*)(ws);                               // 16 KB
    int*            g_idx    = (int*)(ws + (16 << 10));                  // 2 KB
    float*          g_valid  = (float*)(ws + (18 << 10));                // 2 KB
    float*          boxes_ws = (float*)(ws + (20 << 10));                // 96 KB
    unsigned short* maskT    = (unsigned short*)(ws + (116 << 10));      // 512 KB

    rank_kernel<<<BB * 32, 256, 0, stream>>>(scores, proposals, deltas, order, boxes_ws);
    build_kernel<<<dim3(63, BB), 256, 0, stream>>>(boxes_ws, maskT);
    walk_kernel<<<BB, 64, 0, stream>>>(maskT, order, boxes_ws, out_boxes, out_bidx, g_idx, g_valid);
    resize_kernel<<<BB * MAXOUT, 256, 0, stream>>>(masks, g_idx, g_valid, out_masks);
}

// Round 4
// 72.984 us; speedup vs baseline: 1.6705x; 1.6705x over previous
//
#include <hip/hip_runtime.h>
#include <stdint.h>

#define BB 4
#define NN 2000
#define K_PRE 1000
#define KPAD 1024
#define MAXOUT 128
#define NMS_THR 0.3f
#define MASK_IN_VOX (28*28*28)   // 21952
#define MASK_OUT_VOX (32*32*32)  // 32768

// ---------------- rank (stable descending argsort) + regression -------------
__global__ __launch_bounds__(256) void rank_kernel(const float* __restrict__ scores,
                                                   const float* __restrict__ proposals,
                                                   const float* __restrict__ deltas,
                                                   int* __restrict__ order,
                                                   float* __restrict__ boxes_ws) {
    int b = blockIdx.x >> 5;
    int blk = blockIdx.x & 31;
    __shared__ float s[NN];
    const float* sb = scores + b * NN;
    for (int u = threadIdx.x; u < NN / 4; u += 256)
        ((float4*)s)[u] = ((const float4*)sb)[u];
    __syncthreads();

    int i = blk * 64 + (threadIdx.x >> 2);
    int q = threadIdx.x & 3;
    float si = (i < NN) ? s[i] : 0.f;
    int cnt = 0;
    int j0 = q * 500;
    const float4* s4 = (const float4*)s;
#pragma unroll 5
    for (int u = 0; u < 125; ++u) {
        float4 v = s4[j0 / 4 + u];
        int j = j0 + u * 4;
        cnt += (v.x > si) + (v.y > si) + (v.z > si) + (v.w > si);
        cnt += ((v.x == si) & (j + 0 < i)) + ((v.y == si) & (j + 1 < i))
             + ((v.z == si) & (j + 2 < i)) + ((v.w == si) & (j + 3 < i));
    }
    cnt += __shfl_xor(cnt, 1);
    cnt += __shfl_xor(cnt, 2);

    if (q == 0 && i < NN && cnt < K_PRE) {
        int rank = cnt;
        order[b * KPAD + rank] = i;
        const float* p = proposals + (size_t)(b * NN + i) * 6;
        const float* d = deltas    + (size_t)(b * NN + i) * 6;
        float py1 = p[0], px1 = p[1], pz1 = p[2], py2 = p[3], px2 = p[4], pz2 = p[5];
        float h = py2 - py1, w = px2 - px1, dd = pz2 - pz1;
        float cy = py1 + 0.5f * h + d[0] * h;
        float cx = px1 + 0.5f * w + d[1] * w;
        float cz = pz1 + 0.5f * dd + d[2] * dd;
        h *= expf(d[3]); w *= expf(d[4]); dd *= expf(d[5]);
        float* bw = boxes_ws + (size_t)b * 6 * KPAD + rank;
        bw[0 * KPAD] = cy - 0.5f * h;  bw[1 * KPAD] = cx - 0.5f * w;  bw[2 * KPAD] = cz - 0.5f * dd;
        bw[3 * KPAD] = cy + 0.5f * h;  bw[4 * KPAD] = cx + 0.5f * w;  bw[5 * KPAD] = cz + 0.5f * dd;
    }
}

// ---------------- suppression bit-matrix build ------------------------------
// rowBits[(b*KPAD + k)*64 + l] (uint16): bit w <=> IoU(box k, box 64w+l) > thr
// i.e. box j's bit lives at lane j&63, bit j>>6  (ballot-friendly layout)
__global__ __launch_bounds__(256) void build_kernel(const float* __restrict__ boxes_ws,
                                                    unsigned short* __restrict__ rowBits) {
    int b = blockIdx.y;
    int kbase = blockIdx.x * 16;
    __shared__ float sbx[6][1088];     // stride-17 padding: index k + (k>>4)
    int tid = threadIdx.x;
    const float* bw = boxes_ws + (size_t)b * 6 * KPAD;
    for (int k = tid; k < KPAD; k += 256) {
        int ks = k + (k >> 4);
#pragma unroll
        for (int c = 0; c < 6; ++c) sbx[c][ks] = bw[c * KPAD + k];
    }
    __syncthreads();
    int l = tid & 63, lr = tid >> 6;
#pragma unroll
    for (int pss = 0; pss < 4; ++pss) {
        int k = kbase + pss * 4 + lr;             // 0..1023
        int ks = k + (k >> 4);
        float ry1 = sbx[0][ks], rx1 = sbx[1][ks], rz1 = sbx[2][ks];
        float ry2 = sbx[3][ks], rx2 = sbx[4][ks], rz2 = sbx[5][ks];
        float v1 = (ry2 - ry1) * (rx2 - rx1) * (rz2 - rz1);
        uint32_t bits = 0;
#pragma unroll
        for (int w = 0; w < 16; ++w) {
            int j = 64 * w + l;
            int js = j + (j >> 4);
            float y1 = sbx[0][js], x1 = sbx[1][js], z1 = sbx[2][js];
            float y2 = sbx[3][js], x2 = sbx[4][js], z2 = sbx[5][js];
            float iy = fmaxf(fminf(ry2, y2) - fmaxf(ry1, y1), 0.f);
            float ix = fmaxf(fminf(rx2, x2) - fmaxf(rx1, x1), 0.f);
            float iz = fmaxf(fminf(rz2, z2) - fmaxf(rz1, z1), 0.f);
            float inter = iy * ix * iz;
            float v2 = (y2 - y1) * (x2 - x1) * (z2 - z1);
            float iou = inter / (v1 + v2 - inter + 1e-8f);
            bits |= (iou > NMS_THR ? 1u : 0u) << w;
        }
        rowBits[((size_t)(b * KPAD + k)) * 64 + l] = (unsigned short)bits;
    }
}

// ---------------- serial greedy walk (ballot-based, matrix in LDS) ----------
// dynamic LDS: KPAD*64 uint16 = 128 KB (needs hipFuncSetAttribute)
__global__ __launch_bounds__(256) void walk_kernel(const unsigned short* __restrict__ rowBits,
                                                   const int* __restrict__ order,
                                                   const float* __restrict__ boxes_ws,
                                                   float* __restrict__ out_boxes,
                                                   float* __restrict__ out_bidx,
                                                   int* __restrict__ g_idx,
                                                   float* __restrict__ g_valid) {
    extern __shared__ unsigned short rows_lds[];   // [KPAD][64]
    __shared__ short sel_k[MAXOUT];
    int b = blockIdx.x;
    int tid = threadIdx.x;

    // stage the whole bit-matrix into LDS (coalesced, 4 waves)
    const uint4* src4 = (const uint4*)(rowBits + (size_t)b * KPAD * 64);
    uint4* dst4 = (uint4*)rows_lds;
    for (int t = tid; t < KPAD * 64 * 2 / 16; t += 256) dst4[t] = src4[t];
    __syncthreads();
    if (tid >= 64) return;
    int lane = tid;

    // sup bit w of lane l <=> box 64w+l suppressed; pre-suppress pads (>=1000)
    uint32_t sup = (lane >= 40) ? (1u << 15) : 0u;
    int nsel = 0;

    for (int w = 0; w < 16 && nsel < MAXOUT; ++w) {
        unsigned long long m = ~__ballot((int)((sup >> w) & 1u));
        while (m != 0ull && nsel < MAXOUT) {
            int kk = __builtin_ctzll(m);
            int k = (w << 6) + kk;                 // first unsuppressed box (score order)
            unsigned short row = rows_lds[(k << 6) + lane];
            sup |= (uint32_t)row;                  // includes self bit (IoU=1)
            if (lane == 0) sel_k[nsel] = (short)k;
            nsel++;
            m = ~__ballot((int)((sup >> w) & 1u));
        }
    }

    __builtin_amdgcn_s_waitcnt(0);  // lane0's LDS writes -> visible to whole wave
    const float* bw = boxes_ws + (size_t)b * 6 * KPAD;
#pragma unroll
    for (int s0 = 0; s0 < 2; ++s0) {
        int s = lane + s0 * 64;
        int valid = s < nsel;
        int k = valid ? (int)sel_k[s] : 0;
        int idx = valid ? order[b * KPAD + k] : 0;
        float vf = valid ? 1.f : 0.f;
        g_idx[b * MAXOUT + s] = idx;
        g_valid[b * MAXOUT + s] = vf;
        float* ob = out_boxes + (size_t)(b * MAXOUT + s) * 6;
#pragma unroll
        for (int c = 0; c < 6; ++c) ob[c] = bw[c * KPAD + k] * vf;
        out_bidx[b * MAXOUT + s] = (float)b;
    }
}

// ---------------- mask gather + trilinear 28^3 -> 32^3 ----------------------
// thread owns (oy,oz): gathers 4 source rows as float4 (28 loads), zy-lerps
// into a 28-register row, static-unrolled x-pass, LDS-bounced coalesced store.
__global__ __launch_bounds__(256) void resize_kernel(const float* __restrict__ masks,
                                                     const int* __restrict__ g_idx,
                                                     const float* __restrict__ g_valid,
                                                     float* __restrict__ out_masks) {
    int s = blockIdx.x;          // 0..B*MAXOUT-1
    int b = s >> 7;
    int gi = g_idx[s];
    float vf = g_valid[s];
    const float* src = masks + (size_t)(b * NN + gi) * MASK_IN_VOX;
    float* dst = out_masks + (size_t)s * MASK_OUT_VOX;

    __shared__ __align__(16) float rowbuf[4][64 * 36];   // 36-float stride: bank-spread
    int tid = threadIdx.x;
    int lane = tid & 63;
    float* rb = rowbuf[tid >> 6];
    const float4* s4b = (const float4*)src;              // row (z*28+y) -> float4 idx *7

#pragma unroll
    for (int p = 0; p < 4; ++p) {
        int idx = p * 256 + tid;
        int oy = idx & 31, oz = idx >> 5;

        float syf = 0.875f * oy - 0.0625f;
        int fly = (syf >= 0.f) ? (int)syf : -1;
        float fy = syf - (float)fly;
        int y0 = fly < 0 ? 0 : fly;
        int y1 = fly + 1 > 27 ? 27 : fly + 1;

        float szf = 0.875f * oz - 0.0625f;
        int flz = (szf >= 0.f) ? (int)szf : -1;
        float fz = szf - (float)flz;
        int z0 = flz < 0 ? 0 : flz;
        int z1 = flz + 1 > 27 ? 27 : flz + 1;

        float w00 = (1.f - fy) * (1.f - fz);
        float w01 = fy * (1.f - fz);
        float w10 = (1.f - fy) * fz;
        float w11 = fy * fz;

        const float4* r00 = s4b + (z0 * 28 + y0) * 7;
        const float4* r01 = s4b + (z0 * 28 + y1) * 7;
        const float4* r10 = s4b + (z1 * 28 + y0) * 7;
        const float4* r11 = s4b + (z1 * 28 + y1) * 7;

        float c[28];
#pragma unroll
        for (int t = 0; t < 7; ++t) {
            float4 a = r00[t], bb = r01[t], cc = r10[t], dd = r11[t];
            c[4 * t + 0] = a.x * w00 + bb.x * w01 + cc.x * w10 + dd.x * w11;
            c[4 * t + 1] = a.y * w00 + bb.y * w01 + cc.y * w10 + dd.y * w11;
            c[4 * t + 2] = a.z * w00 + bb.z * w01 + cc.z * w10 + dd.z * w11;
            c[4 * t + 3] = a.w * w00 + bb.w * w01 + cc.w * w10 + dd.w * w11;
        }

        // x-pass: fully unrolled, compile-time x0/x1/fx -> c[] stays in registers
#pragma unroll
        for (int e = 0; e < 8; ++e) {
            float4 o;
#pragma unroll
            for (int qq = 0; qq < 4; ++qq) {
                const int ox = e * 4 + qq;
                const float sx = 0.875f * (float)ox - 0.0625f;
                const int flx = (ox == 0) ? -1 : (14 * ox - 1) / 16;
                const float fx = sx - (float)flx;
                const int x0 = flx < 0 ? 0 : flx;
                const int x1 = flx + 1 > 27 ? 27 : flx + 1;
                (&o.x)[qq] = (c[x0] + fx * (c[x1] - c[x0])) * vf;
            }
            *(float4*)&rb[lane * 36 + e * 4] = o;
        }

        // coalesced copy-out: wave's 64 rows are contiguous in the output
        float4* dchunk = (float4*)dst + (size_t)(p * 256 + (tid & ~63)) * 8;
#pragma unroll
        for (int t = 0; t < 8; ++t) {
            int f = t * 64 + lane;
            float4 v = *(const float4*)&rb[(f >> 3) * 36 + (f & 7) * 4];
            dchunk[f] = v;
        }
    }
}

extern "C" void kernel_launch(void* const* d_in, const int* in_sizes, int n_in,
                              void* d_out, int out_size, void* d_ws, size_t ws_size,
                              hipStream_t stream) {
    const float* proposals = (const float*)d_in[0];
    const float* scores    = (const float*)d_in[1];
    const float* deltas    = (const float*)d_in[2];
    const float* masks     = (const float*)d_in[3];

    float* out = (float*)d_out;
    float* out_boxes = out;                                              // [512,6]
    float* out_masks = out + (size_t)BB * MAXOUT * 6;                    // [512,32768]
    float* out_bidx  = out + (size_t)BB * MAXOUT * 6 + (size_t)BB * MAXOUT * MASK_OUT_VOX;

    char* ws = (char*)d_ws;
    int*            order    = (int*)(ws);                               // 16 KB
    int*            g_idx    = (int*)(ws + (16 << 10));                  // 2 KB
    float*          g_valid  = (float*)(ws + (18 << 10));                // 2 KB
    float*          boxes_ws = (float*)(ws + (20 << 10));                // 96 KB
    unsigned short* rowBits  = (unsigned short*)(ws + (116 << 10));      // 512 KB

    static int attr_set = 0;  // host-side only; setting an attribute is idempotent & capture-safe
    if (!attr_set) {
        hipFuncSetAttribute(reinterpret_cast<const void*>(walk_kernel),
                            hipFuncAttributeMaxDynamicSharedMemorySize, KPAD * 64 * 2);
        attr_set = 1;
    }

    rank_kernel<<<BB * 32, 256, 0, stream>>>(scores, proposals, deltas, order, boxes_ws);
    build_kernel<<<dim3(64, BB), 256, 0, stream>>>(boxes_ws, rowBits);
    walk_kernel<<<BB, 256, KPAD * 64 * 2, stream>>>(rowBits, order, boxes_ws,
                                                    out_boxes, out_bidx, g_idx, g_valid);
    resize_kernel<<<BB * MAXOUT, 256, 0, stream>>>(masks, g_idx, g_valid, out_masks);
}